// Round 1
// baseline (933.198 us; speedup 1.0000x reference)
//
#include <hip/hip_runtime.h>
#include <hip/hip_bf16.h>
#include <float.h>

#define BATCHES 256
#define NPB     512            // nodes per batch
#define NN      (BATCHES*NPB)  // 131072 total nodes
#define KNN     16
#define KP      17
#define DIN     32
#define DH      128
#define DOUT    8
#define SCAN_CHUNK 1024

// ---------------------------------------------------------------- KNN
// One block per batch, one thread per node. Top-17 smallest (dist, idx)
// via stable sorted insertion (ascending idx order + strict < replicates
// jax.lax.top_k tie-breaking). Element 0 == self; emit elements 1..16.
// Distance arithmetic mirrors the reference's f32 rounding exactly
// (no FMA contraction).
__global__ __launch_bounds__(NPB) void knn_kernel(
    const float* __restrict__ obs, int* __restrict__ nbr, int* __restrict__ indeg) {
  __shared__ float px[NPB], py[NPB], sq[NPB];
  const int b = blockIdx.x;
  const int n = threadIdx.x;
  const float* orow = obs + ((size_t)b * NPB + n) * DIN;
  const float x = orow[0], y = orow[1];
  const float s = __fadd_rn(__fmul_rn(x, x), __fmul_rn(y, y));
  px[n] = x; py[n] = y; sq[n] = s;
  __syncthreads();

  float dl[KP]; int il[KP];
#pragma unroll
  for (int j = 0; j < KP; ++j) { dl[j] = FLT_MAX; il[j] = -1; }

  for (int j = 0; j < NPB; ++j) {
    const float dot = __fadd_rn(__fmul_rn(x, px[j]), __fmul_rn(y, py[j]));
    const float d2  = __fsub_rn(__fadd_rn(s, sq[j]), __fmul_rn(2.0f, dot));
    const float dc  = sqrtf(fmaxf(d2, 0.0f));
    if (dc < dl[KP - 1]) {
      bool shp = true;  // "belongs at or below slot KP-1"
#pragma unroll
      for (int t = KP - 1; t >= 1; --t) {
        const bool sh = dc < dl[t - 1];
        const float nd = sh ? dl[t - 1] : (shp ? dc : dl[t]);
        const int   ni = sh ? il[t - 1] : (shp ? j  : il[t]);
        dl[t] = nd; il[t] = ni;
        shp = sh;
      }
      if (shp) { dl[0] = dc; il[0] = j; }
    }
  }

  const int base = (b * NPB + n) * KNN;
#pragma unroll
  for (int k = 0; k < KNN; ++k) {
    const int g = b * NPB + il[k + 1];
    nbr[base + k] = g;
    atomicAdd(&indeg[g], 1);
  }
}

// ---------------------------------------------------------------- scan
__global__ __launch_bounds__(256) void scan_phaseA(
    const int* __restrict__ indeg, int* __restrict__ bsum) {
  __shared__ int sh[256];
  const int base = blockIdx.x * SCAN_CHUNK;
  const int t = threadIdx.x;
  int sum = 0;
  for (int j = t; j < SCAN_CHUNK; j += 256) sum += indeg[base + j];
  sh[t] = sum; __syncthreads();
  for (int o = 128; o > 0; o >>= 1) {
    if (t < o) sh[t] += sh[t + o];
    __syncthreads();
  }
  if (t == 0) bsum[blockIdx.x] = sh[0];
}

__global__ void scan_phaseB(int* bsum, int nb) {
  if (threadIdx.x == 0 && blockIdx.x == 0) {
    int acc = 0;
    for (int i = 0; i < nb; ++i) { int v = bsum[i]; bsum[i] = acc; acc += v; }
  }
}

__global__ __launch_bounds__(256) void scan_phaseC(
    const int* __restrict__ indeg, const int* __restrict__ bsum,
    int* __restrict__ offs) {
  __shared__ int sh[256];
  const int base = blockIdx.x * SCAN_CHUNK;
  const int t = threadIdx.x;
  const int e0 = base + t * 4;
  const int v0 = indeg[e0], v1 = indeg[e0 + 1], v2 = indeg[e0 + 2], v3 = indeg[e0 + 3];
  const int tot = v0 + v1 + v2 + v3;
  sh[t] = tot; __syncthreads();
  for (int o = 1; o < 256; o <<= 1) {
    const int a = sh[t];
    const int bm = (t >= o) ? sh[t - o] : 0;
    __syncthreads();
    sh[t] = a + bm;
    __syncthreads();
  }
  const int pre = sh[t] - tot + bsum[blockIdx.x];
  offs[e0] = pre;
  offs[e0 + 1] = pre + v0;
  offs[e0 + 2] = pre + v0 + v1;
  offs[e0 + 3] = pre + v0 + v1 + v2;
}

// ------------------------------------------------------- CSR fill + dinv
__global__ __launch_bounds__(256) void fill_kernel(
    const int* __restrict__ nbr, const int* __restrict__ offs,
    int* __restrict__ fill, int* __restrict__ rev,
    const int* __restrict__ indeg, float* __restrict__ dinv) {
  const int i = blockIdx.x * blockDim.x + threadIdx.x;
  if (i >= NN) return;
  dinv[i] = 1.0f / sqrtf((float)(indeg[i] + 1));
#pragma unroll
  for (int k = 0; k < KNN; ++k) {
    const int v = nbr[i * KNN + k];
    const int p = offs[v] + atomicAdd(&fill[v], 1);
    rev[p] = i;
  }
}

// ---------------------------------------------------------------- GEMM
// Block computes 32 rows x 128 cols. Thread = 4 rows x 4 cols.
template <int KDIM>
__global__ __launch_bounds__(256) void gemm_kernel(
    const float* __restrict__ X, const float* __restrict__ W,
    float* __restrict__ H) {
  __shared__ float ws[32][DH];   // k-chunk of W
  __shared__ float xs[32][32];   // rows x k-chunk
  const int tid = threadIdx.x;
  const int tx = tid & 31;   // col group: cols 4tx..4tx+3
  const int ty = tid >> 5;   // row group: rows 4ty..4ty+3
  const int rowBase = blockIdx.x * 32;
  float acc[4][4] = {};

  for (int kb = 0; kb < KDIM; kb += 32) {
    // stage W chunk (32x128)
    for (int l = tid; l < 32 * DH / 4; l += 256) {
      const int kk = l >> 5;
      const int cc = (l & 31) * 4;
      const float4 w4 = *(const float4*)&W[(size_t)(kb + kk) * DH + cc];
      *(float4*)&ws[kk][cc] = w4;
    }
    // stage X chunk (32 rows x 32 k)
    for (int l = tid; l < 32 * 32 / 4; l += 256) {
      const int rr = l >> 3;
      const int kk = (l & 7) * 4;
      const float4 x4 = *(const float4*)&X[((size_t)rowBase + rr) * KDIM + kb + kk];
      *(float4*)&xs[rr][kk] = x4;
    }
    __syncthreads();
#pragma unroll 8
    for (int k = 0; k < 32; ++k) {
      const float4 w4 = *(const float4*)&ws[k][tx * 4];
      const float a0 = xs[ty * 4 + 0][k];
      const float a1 = xs[ty * 4 + 1][k];
      const float a2 = xs[ty * 4 + 2][k];
      const float a3 = xs[ty * 4 + 3][k];
      acc[0][0] += a0 * w4.x; acc[0][1] += a0 * w4.y; acc[0][2] += a0 * w4.z; acc[0][3] += a0 * w4.w;
      acc[1][0] += a1 * w4.x; acc[1][1] += a1 * w4.y; acc[1][2] += a1 * w4.z; acc[1][3] += a1 * w4.w;
      acc[2][0] += a2 * w4.x; acc[2][1] += a2 * w4.y; acc[2][2] += a2 * w4.z; acc[2][3] += a2 * w4.w;
      acc[3][0] += a3 * w4.x; acc[3][1] += a3 * w4.y; acc[3][2] += a3 * w4.z; acc[3][3] += a3 * w4.w;
    }
    __syncthreads();
  }
#pragma unroll
  for (int r = 0; r < 4; ++r) {
    const float4 o = make_float4(acc[r][0], acc[r][1], acc[r][2], acc[r][3]);
    *(float4*)&H[((size_t)rowBase + ty * 4 + r) * DH + tx * 4] = o;
  }
}

// ------------------------------------------------------------- aggregate
// One wave per node; lane handles 2 feature dims (64*2 = 128).
__global__ __launch_bounds__(256) void agg_kernel(
    const float* __restrict__ H, const int* __restrict__ offs,
    const int* __restrict__ indeg, const int* __restrict__ rev,
    const float* __restrict__ dinv, const float* __restrict__ bias,
    float* __restrict__ Xout) {
  const int gtid = blockIdx.x * blockDim.x + threadIdx.x;
  const int v = gtid >> 6;
  const int lane = threadIdx.x & 63;
  if (v >= NN) return;
  const float dv = dinv[v];
  const float2 hself = *(const float2*)(H + (size_t)v * DH + lane * 2);
  float ax = hself.x * (dv * dv);
  float ay = hself.y * (dv * dv);
  const int beg = offs[v];
  const int len = indeg[v];
  for (int e = 0; e < len; ++e) {
    const int i = rev[beg + e];
    const float sc = dinv[i] * dv;
    const float2 hi = *(const float2*)(H + (size_t)i * DH + lane * 2);
    ax += hi.x * sc;
    ay += hi.y * sc;
  }
  const float ox = tanhf(ax + bias[lane * 2]);
  const float oy = tanhf(ay + bias[lane * 2 + 1]);
  *(float2*)(Xout + (size_t)v * DH + lane * 2) = make_float2(ox, oy);
}

// ------------------------------------------------------------ output head
__global__ __launch_bounds__(256) void out_kernel(
    const float* __restrict__ X, const float* __restrict__ Wout,
    const float* __restrict__ bout, float* __restrict__ out) {
  __shared__ float ws[DH * DOUT];
  __shared__ float bs[DOUT];
  const int tid = threadIdx.x;
  for (int l = tid; l < DH * DOUT; l += 256) ws[l] = Wout[l];
  if (tid < DOUT) bs[tid] = bout[tid];
  __syncthreads();
  const int node = blockIdx.x * 256 + tid;
  float acc[DOUT];
#pragma unroll
  for (int o = 0; o < DOUT; ++o) acc[o] = bs[o];
  const float4* xr = (const float4*)(X + (size_t)node * DH);
#pragma unroll 4
  for (int k4 = 0; k4 < DH / 4; ++k4) {
    const float4 x4 = xr[k4];
#pragma unroll
    for (int o = 0; o < DOUT; ++o) {
      acc[o] += x4.x * ws[(k4 * 4 + 0) * DOUT + o]
              + x4.y * ws[(k4 * 4 + 1) * DOUT + o]
              + x4.z * ws[(k4 * 4 + 2) * DOUT + o]
              + x4.w * ws[(k4 * 4 + 3) * DOUT + o];
    }
  }
  float4* op = (float4*)(out + (size_t)node * DOUT);
  op[0] = make_float4(acc[0], acc[1], acc[2], acc[3]);
  op[1] = make_float4(acc[4], acc[5], acc[6], acc[7]);
}

// ---------------------------------------------------------------- launch
extern "C" void kernel_launch(void* const* d_in, const int* in_sizes, int n_in,
                              void* d_out, int out_size, void* d_ws, size_t ws_size,
                              hipStream_t stream) {
  const float* obs  = (const float*)d_in[0];
  const float* W1   = (const float*)d_in[1];
  const float* b1   = (const float*)d_in[2];
  const float* W2   = (const float*)d_in[3];
  const float* b2   = (const float*)d_in[4];
  const float* Wout = (const float*)d_in[5];
  const float* bout = (const float*)d_in[6];
  float* out = (float*)d_out;

  char* p = (char*)d_ws;
  auto carve = [&](size_t bytes) {
    void* r = (void*)p;
    p += (bytes + 255) / 256 * 256;
    return r;
  };
  float* h    = (float*)carve((size_t)NN * DH * 4);
  float* x1   = (float*)carve((size_t)NN * DH * 4);
  int*   nbr  = (int*)carve((size_t)NN * KNN * 4);
  int*   indeg= (int*)carve((size_t)NN * 4);
  int*   offs = (int*)carve((size_t)NN * 4);
  int*   fil  = (int*)carve((size_t)NN * 4);
  int*   rev  = (int*)carve((size_t)NN * KNN * 4);
  float* dinv = (float*)carve((size_t)NN * 4);
  int*   bsum = (int*)carve(256 * 4);

  hipMemsetAsync(indeg, 0, (size_t)NN * 4, stream);
  hipMemsetAsync(fil,   0, (size_t)NN * 4, stream);

  // graph build
  knn_kernel<<<BATCHES, NPB, 0, stream>>>(obs, nbr, indeg);
  scan_phaseA<<<NN / SCAN_CHUNK, 256, 0, stream>>>(indeg, bsum);
  scan_phaseB<<<1, 64, 0, stream>>>(bsum, NN / SCAN_CHUNK);
  scan_phaseC<<<NN / SCAN_CHUNK, 256, 0, stream>>>(indeg, bsum, offs);
  fill_kernel<<<NN / 256, 256, 0, stream>>>(nbr, offs, fil, rev, indeg, dinv);

  // layer 1: h = obs @ W1 ; x1 = tanh(agg + b1)
  gemm_kernel<DIN><<<NN / 32, 256, 0, stream>>>(obs, W1, h);
  agg_kernel<<<NN * 64 / 256, 256, 0, stream>>>(h, offs, indeg, rev, dinv, b1, x1);

  // layer 2: h = x1 @ W2 ; x1 = tanh(agg + b2)
  gemm_kernel<DH><<<NN / 32, 256, 0, stream>>>(x1, W2, h);
  agg_kernel<<<NN * 64 / 256, 256, 0, stream>>>(h, offs, indeg, rev, dinv, b2, x1);

  // output head
  out_kernel<<<NN / 256, 256, 0, stream>>>(x1, Wout, bout, out);
}

// Round 3
// 804.385 us; speedup vs baseline: 1.1601x; 1.1601x over previous
//
#include <hip/hip_runtime.h>
#include <hip/hip_bf16.h>
#include <float.h>

#define BATCHES 256
#define NPB     512            // nodes per batch
#define NN      (BATCHES*NPB)  // 131072 total nodes
#define KNN     16
#define KP      17
#define DIN     32
#define DH      128
#define DOUT    8
#define SCAN_CHUNK 1024

// ---------------------------------------------------------------- KNN
// 2 threads per node scan disjoint 256-candidate halves with the verified
// sorted-insertion top-17 (lex (dist,idx) order == jax.lax.top_k ties).
// Merge fix (round-2 crash): both lanes build the CANONICAL ordered pair
// (A = part0's list, B = part1's list) before the bitonic half-clean, so
// md/mi/minpos/slot are identical across the lane pair and the parity
// split covers output slots 0..15 bijectively.
__global__ __launch_bounds__(256) void knn_kernel(
    const float* __restrict__ obs, int* __restrict__ nbr, int* __restrict__ indeg) {
  __shared__ float px[NPB], py[NPB], sq[NPB];
  const int b = blockIdx.x >> 2;          // 4 blocks per batch
  const int quarter = blockIdx.x & 3;     // which 128-node quarter
  const int tid = threadIdx.x;
  const int part = tid & 1;               // candidate half owned
  const int nl = (tid >> 1) + quarter * 128;  // local node 0..511

  // stage all 512 positions of this batch
  for (int l = tid; l < NPB; l += 256) {
    const float* orow = obs + ((size_t)b * NPB + l) * DIN;
    const float xx = orow[0], yy = orow[1];
    px[l] = xx; py[l] = yy;
    sq[l] = __fadd_rn(__fmul_rn(xx, xx), __fmul_rn(yy, yy));
  }
  __syncthreads();

  const float x = px[nl], y = py[nl], s = sq[nl];

  float dl[KP]; int il[KP];
#pragma unroll
  for (int j = 0; j < KP; ++j) { dl[j] = FLT_MAX; il[j] = -1; }

  const int jbase = part * 256;
  for (int jj = 0; jj < 256; ++jj) {
    const int j = jbase + jj;
    const float dot = __fadd_rn(__fmul_rn(x, px[j]), __fmul_rn(y, py[j]));
    const float d2  = __fsub_rn(__fadd_rn(s, sq[j]), __fmul_rn(2.0f, dot));
    const float dc  = sqrtf(fmaxf(d2, 0.0f));
    if (dc < dl[KP - 1]) {
      bool shp = true;
#pragma unroll
      for (int t = KP - 1; t >= 1; --t) {
        const bool sh = dc < dl[t - 1];
        const float nd = sh ? dl[t - 1] : (shp ? dc : dl[t]);
        const int   ni = sh ? il[t - 1] : (shp ? j  : il[t]);
        dl[t] = nd; il[t] = ni;
        shp = sh;
      }
      if (shp) { dl[0] = dc; il[0] = j; }
    }
  }

  // exchange partner's sorted list (lane^1, same wave) and canonicalize:
  // A = part0's list, B = part1's list — identical on both lanes.
  float Ad[KP], Bd[KP]; int Ai[KP], Bi[KP];
#pragma unroll
  for (int t = 0; t < KP; ++t) {
    const float o_d = __shfl_xor(dl[t], 1);
    const int   o_i = __shfl_xor(il[t], 1);
    Ad[t] = part ? o_d : dl[t];
    Ai[t] = part ? o_i : il[t];
    Bd[t] = part ? dl[t] : o_d;
    Bi[t] = part ? il[t] : o_i;
  }
  // half-clean: md[i] = lexmin(A[i], B[16-i]) -> smallest-17 multiset,
  // same array on both lanes.
  float md[KP]; int mi[KP];
#pragma unroll
  for (int i = 0; i < KP; ++i) {
    const float da = Ad[i], db = Bd[KP - 1 - i];
    const int   ia = Ai[i], ib = Bi[KP - 1 - i];
    const bool aless = (da < db) || (da == db && ia < ib);
    md[i] = aless ? da : db;
    mi[i] = aless ? ia : ib;
  }
  // find lex-min (== reference's dropped element 0, normally self)
  int minpos = 0;
#pragma unroll
  for (int i = 1; i < KP; ++i) {
    const bool less = (md[i] < md[minpos]) ||
                      (md[i] == md[minpos] && mi[i] < mi[minpos]);
    minpos = less ? i : minpos;
  }
  // emit 16 neighbors; lane pair splits by parity of i (consistent slots)
  const int base = (b * NPB + nl) * KNN;
#pragma unroll
  for (int i = 0; i < KP; ++i) {
    if ((i & 1) == part && i != minpos) {
      const int slot = i - (i > minpos ? 1 : 0);
      const int g = b * NPB + mi[i];
      nbr[base + slot] = g;
      atomicAdd(&indeg[g], 1);
    }
  }
}

// ---------------------------------------------------------------- scan
__global__ __launch_bounds__(256) void scan_phaseA(
    const int* __restrict__ indeg, int* __restrict__ bsum) {
  __shared__ int sh[256];
  const int base = blockIdx.x * SCAN_CHUNK;
  const int t = threadIdx.x;
  int sum = 0;
  for (int j = t; j < SCAN_CHUNK; j += 256) sum += indeg[base + j];
  sh[t] = sum; __syncthreads();
  for (int o = 128; o > 0; o >>= 1) {
    if (t < o) sh[t] += sh[t + o];
    __syncthreads();
  }
  if (t == 0) bsum[blockIdx.x] = sh[0];
}

__global__ void scan_phaseB(int* bsum, int nb) {
  if (threadIdx.x == 0 && blockIdx.x == 0) {
    int acc = 0;
    for (int i = 0; i < nb; ++i) { int v = bsum[i]; bsum[i] = acc; acc += v; }
  }
}

__global__ __launch_bounds__(256) void scan_phaseC(
    const int* __restrict__ indeg, const int* __restrict__ bsum,
    int* __restrict__ offs) {
  __shared__ int sh[256];
  const int base = blockIdx.x * SCAN_CHUNK;
  const int t = threadIdx.x;
  const int e0 = base + t * 4;
  const int v0 = indeg[e0], v1 = indeg[e0 + 1], v2 = indeg[e0 + 2], v3 = indeg[e0 + 3];
  const int tot = v0 + v1 + v2 + v3;
  sh[t] = tot; __syncthreads();
  for (int o = 1; o < 256; o <<= 1) {
    const int a = sh[t];
    const int bm = (t >= o) ? sh[t - o] : 0;
    __syncthreads();
    sh[t] = a + bm;
    __syncthreads();
  }
  const int pre = sh[t] - tot + bsum[blockIdx.x];
  offs[e0] = pre;
  offs[e0 + 1] = pre + v0;
  offs[e0 + 2] = pre + v0 + v1;
  offs[e0 + 3] = pre + v0 + v1 + v2;
}

// ------------------------------------------------------- CSR fill + dinv
__global__ __launch_bounds__(256) void fill_kernel(
    const int* __restrict__ nbr, const int* __restrict__ offs,
    int* __restrict__ fill, int* __restrict__ rev,
    const int* __restrict__ indeg, float* __restrict__ dinv) {
  const int i = blockIdx.x * blockDim.x + threadIdx.x;
  if (i >= NN) return;
  dinv[i] = 1.0f / sqrtf((float)(indeg[i] + 1));
#pragma unroll
  for (int k = 0; k < KNN; ++k) {
    const int v = nbr[i * KNN + k];
    const int p = offs[v] + atomicAdd(&fill[v], 1);
    rev[p] = i;
  }
}

// ---------------------------------------------------------------- GEMM
// Block computes 32 rows x 128 cols. Thread = 4 rows x 4 cols.
template <int KDIM>
__global__ __launch_bounds__(256) void gemm_kernel(
    const float* __restrict__ X, const float* __restrict__ W,
    float* __restrict__ H) {
  __shared__ float ws[32][DH];   // k-chunk of W
  __shared__ float xs[32][32];   // rows x k-chunk
  const int tid = threadIdx.x;
  const int tx = tid & 31;   // col group: cols 4tx..4tx+3
  const int ty = tid >> 5;   // row group: rows 4ty..4ty+3
  const int rowBase = blockIdx.x * 32;
  float acc[4][4] = {};

  for (int kb = 0; kb < KDIM; kb += 32) {
    for (int l = tid; l < 32 * DH / 4; l += 256) {
      const int kk = l >> 5;
      const int cc = (l & 31) * 4;
      const float4 w4 = *(const float4*)&W[(size_t)(kb + kk) * DH + cc];
      *(float4*)&ws[kk][cc] = w4;
    }
    for (int l = tid; l < 32 * 32 / 4; l += 256) {
      const int rr = l >> 3;
      const int kk = (l & 7) * 4;
      const float4 x4 = *(const float4*)&X[((size_t)rowBase + rr) * KDIM + kb + kk];
      *(float4*)&xs[rr][kk] = x4;
    }
    __syncthreads();
#pragma unroll 8
    for (int k = 0; k < 32; ++k) {
      const float4 w4 = *(const float4*)&ws[k][tx * 4];
      const float a0 = xs[ty * 4 + 0][k];
      const float a1 = xs[ty * 4 + 1][k];
      const float a2 = xs[ty * 4 + 2][k];
      const float a3 = xs[ty * 4 + 3][k];
      acc[0][0] += a0 * w4.x; acc[0][1] += a0 * w4.y; acc[0][2] += a0 * w4.z; acc[0][3] += a0 * w4.w;
      acc[1][0] += a1 * w4.x; acc[1][1] += a1 * w4.y; acc[1][2] += a1 * w4.z; acc[1][3] += a1 * w4.w;
      acc[2][0] += a2 * w4.x; acc[2][1] += a2 * w4.y; acc[2][2] += a2 * w4.z; acc[2][3] += a2 * w4.w;
      acc[3][0] += a3 * w4.x; acc[3][1] += a3 * w4.y; acc[3][2] += a3 * w4.z; acc[3][3] += a3 * w4.w;
    }
    __syncthreads();
  }
#pragma unroll
  for (int r = 0; r < 4; ++r) {
    const float4 o = make_float4(acc[r][0], acc[r][1], acc[r][2], acc[r][3]);
    *(float4*)&H[((size_t)rowBase + ty * 4 + r) * DH + tx * 4] = o;
  }
}

// ------------------------------------------------------------- aggregate
// One wave per node; lane handles 2 feature dims (64*2 = 128).
__global__ __launch_bounds__(256) void agg_kernel(
    const float* __restrict__ H, const int* __restrict__ offs,
    const int* __restrict__ indeg, const int* __restrict__ rev,
    const float* __restrict__ dinv, const float* __restrict__ bias,
    float* __restrict__ Xout) {
  const int gtid = blockIdx.x * blockDim.x + threadIdx.x;
  const int v = gtid >> 6;
  const int lane = threadIdx.x & 63;
  if (v >= NN) return;
  const float dv = dinv[v];
  const float2 hself = *(const float2*)(H + (size_t)v * DH + lane * 2);
  float ax = hself.x * (dv * dv);
  float ay = hself.y * (dv * dv);
  const int beg = offs[v];
  const int len = indeg[v];
  for (int e = 0; e < len; ++e) {
    const int i = rev[beg + e];
    const float sc = dinv[i] * dv;
    const float2 hi = *(const float2*)(H + (size_t)i * DH + lane * 2);
    ax += hi.x * sc;
    ay += hi.y * sc;
  }
  const float ox = tanhf(ax + bias[lane * 2]);
  const float oy = tanhf(ay + bias[lane * 2 + 1]);
  *(float2*)(Xout + (size_t)v * DH + lane * 2) = make_float2(ox, oy);
}

// ------------------------------------------------------------ output head
__global__ __launch_bounds__(256) void out_kernel(
    const float* __restrict__ X, const float* __restrict__ Wout,
    const float* __restrict__ bout, float* __restrict__ out) {
  __shared__ float ws[DH * DOUT];
  __shared__ float bs[DOUT];
  const int tid = threadIdx.x;
  for (int l = tid; l < DH * DOUT; l += 256) ws[l] = Wout[l];
  if (tid < DOUT) bs[tid] = bout[tid];
  __syncthreads();
  const int node = blockIdx.x * 256 + tid;
  float acc[DOUT];
#pragma unroll
  for (int o = 0; o < DOUT; ++o) acc[o] = bs[o];
  const float4* xr = (const float4*)(X + (size_t)node * DH);
#pragma unroll 4
  for (int k4 = 0; k4 < DH / 4; ++k4) {
    const float4 x4 = xr[k4];
#pragma unroll
    for (int o = 0; o < DOUT; ++o) {
      acc[o] += x4.x * ws[(k4 * 4 + 0) * DOUT + o]
              + x4.y * ws[(k4 * 4 + 1) * DOUT + o]
              + x4.z * ws[(k4 * 4 + 2) * DOUT + o]
              + x4.w * ws[(k4 * 4 + 3) * DOUT + o];
    }
  }
  float4* op = (float4*)(out + (size_t)node * DOUT);
  op[0] = make_float4(acc[0], acc[1], acc[2], acc[3]);
  op[1] = make_float4(acc[4], acc[5], acc[6], acc[7]);
}

// ---------------------------------------------------------------- launch
extern "C" void kernel_launch(void* const* d_in, const int* in_sizes, int n_in,
                              void* d_out, int out_size, void* d_ws, size_t ws_size,
                              hipStream_t stream) {
  const float* obs  = (const float*)d_in[0];
  const float* W1   = (const float*)d_in[1];
  const float* b1   = (const float*)d_in[2];
  const float* W2   = (const float*)d_in[3];
  const float* b2   = (const float*)d_in[4];
  const float* Wout = (const float*)d_in[5];
  const float* bout = (const float*)d_in[6];
  float* out = (float*)d_out;

  char* p = (char*)d_ws;
  auto carve = [&](size_t bytes) {
    void* r = (void*)p;
    p += (bytes + 255) / 256 * 256;
    return r;
  };
  float* h    = (float*)carve((size_t)NN * DH * 4);
  float* x1   = (float*)carve((size_t)NN * DH * 4);
  int*   nbr  = (int*)carve((size_t)NN * KNN * 4);
  int*   indeg= (int*)carve((size_t)NN * 4);
  int*   offs = (int*)carve((size_t)NN * 4);
  int*   fil  = (int*)carve((size_t)NN * 4);
  int*   rev  = (int*)carve((size_t)NN * KNN * 4);
  float* dinv = (float*)carve((size_t)NN * 4);
  int*   bsum = (int*)carve(256 * 4);

  hipMemsetAsync(indeg, 0, (size_t)NN * 4, stream);
  hipMemsetAsync(fil,   0, (size_t)NN * 4, stream);

  // graph build
  knn_kernel<<<BATCHES * 4, 256, 0, stream>>>(obs, nbr, indeg);
  scan_phaseA<<<NN / SCAN_CHUNK, 256, 0, stream>>>(indeg, bsum);
  scan_phaseB<<<1, 64, 0, stream>>>(bsum, NN / SCAN_CHUNK);
  scan_phaseC<<<NN / SCAN_CHUNK, 256, 0, stream>>>(indeg, bsum, offs);
  fill_kernel<<<NN / 256, 256, 0, stream>>>(nbr, offs, fil, rev, indeg, dinv);

  // layer 1: h = obs @ W1 ; x1 = tanh(agg + b1)
  gemm_kernel<DIN><<<NN / 32, 256, 0, stream>>>(obs, W1, h);
  agg_kernel<<<NN * 64 / 256, 256, 0, stream>>>(h, offs, indeg, rev, dinv, b1, x1);

  // layer 2: h = x1 @ W2 ; x1 = tanh(agg + b2)
  gemm_kernel<DH><<<NN / 32, 256, 0, stream>>>(x1, W2, h);
  agg_kernel<<<NN * 64 / 256, 256, 0, stream>>>(h, offs, indeg, rev, dinv, b2, x1);

  // output head
  out_kernel<<<NN / 256, 256, 0, stream>>>(x1, Wout, bout, out);
}

// Round 4
// 615.306 us; speedup vs baseline: 1.5166x; 1.3073x over previous
//
#include <hip/hip_runtime.h>
#include <hip/hip_bf16.h>
#include <float.h>

#define BATCHES 256
#define NPB     512            // nodes per batch
#define NN      (BATCHES*NPB)  // 131072 total nodes
#define KNN     16
#define KP      17
#define DIN     32
#define DH      128
#define DOUT    8
#define SCAN_CHUNK 1024
#define BUFS    32             // phase-2 collection slots per thread

// ---------------------------------------------------------------- KNN
// Two-phase exact selection, 2 threads per node (disjoint 256-halves).
// P1: top-17 d^2 VALUES only, via unconditional min/max bubble (2 ops/slot,
//     no index tracking, no sqrt). d^2 order maps monotonically onto the
//     reference's dist = sqrtf(max(d2,0)) order, so the 17th-smallest dist
//     of the union = sqrtf(max(d2_(17),0)).
// P2: rescan with the reference-exact dc; collect j where dc <= thr into a
//     per-thread LDS buffer (superset of top-17: top-17 + boundary ties).
// Final: lex (dist,idx) top-17 over collected items via the R3-verified
//     insertion chain; R3-verified canonical merge + minpos + parity emit.
__global__ __launch_bounds__(256) void knn_kernel(
    const float* __restrict__ obs, int* __restrict__ nbr, int* __restrict__ indeg) {
  __shared__ float2 pxy[NPB];
  __shared__ float sqs[NPB];
  __shared__ unsigned short buf[256 * BUFS];   // 16 KiB
  const int b = blockIdx.x >> 2;          // 4 blocks per batch
  const int quarter = blockIdx.x & 3;
  const int tid = threadIdx.x;
  const int part = tid & 1;               // candidate half owned
  const int nl = (tid >> 1) + quarter * 128;

  for (int l = tid; l < NPB; l += 256) {
    const float* orow = obs + ((size_t)b * NPB + l) * DIN;
    const float xx = orow[0], yy = orow[1];
    pxy[l] = make_float2(xx, yy);
    sqs[l] = __fadd_rn(__fmul_rn(xx, xx), __fmul_rn(yy, yy));
  }
  __syncthreads();

  const float2 p0 = pxy[nl];
  const float x = p0.x, y = p0.y, s = sqs[nl];
  const int jbase = part * 256;

  // ---------- phase 1: top-17 d2 values (min/max bubble, unconditional)
  float dl[KP];
#pragma unroll
  for (int t = 0; t < KP; ++t) dl[t] = FLT_MAX;

  for (int jj = 0; jj < 256; ++jj) {
    const int j = jbase + jj;
    const float2 pj = pxy[j];
    const float dot = __fadd_rn(__fmul_rn(x, pj.x), __fmul_rn(y, pj.y));
    float carry = __fsub_rn(__fadd_rn(s, sqs[j]), __fmul_rn(2.0f, dot));
#pragma unroll
    for (int t = 0; t < KP; ++t) {
      const float lo = fminf(dl[t], carry);
      carry = fmaxf(dl[t], carry);
      dl[t] = lo;
    }
  }

  // ---------- threshold: 17th-smallest d2 of the lane-pair union
  // (bitonic half-clean of two sorted ascending lists; max of low set)
  float thr2 = -FLT_MAX;
#pragma unroll
  for (int i = 0; i < KP; ++i) {
    const float ob = __shfl_xor(dl[KP - 1 - i], 1);
    thr2 = fmaxf(thr2, fminf(dl[i], ob));
  }
  const float thr = sqrtf(fmaxf(thr2, 0.0f));

  // ---------- phase 2: collect candidates with reference-exact dc <= thr
  int cnt = 0;
  const int bufbase = tid * BUFS;
  for (int jj = 0; jj < 256; ++jj) {
    const int j = jbase + jj;
    const float2 pj = pxy[j];
    const float dot = __fadd_rn(__fmul_rn(x, pj.x), __fmul_rn(y, pj.y));
    const float d2  = __fsub_rn(__fadd_rn(s, sqs[j]), __fmul_rn(2.0f, dot));
    const float dc  = sqrtf(fmaxf(d2, 0.0f));
    if (dc <= thr && cnt < BUFS) {
      buf[bufbase + cnt] = (unsigned short)j;
      ++cnt;
    }
  }

  // ---------- final: lex (dist, idx) top-17 of own collected items
  // (ascending-j buffer order + strict-< chain == stable top_k ties)
  float fd[KP]; int fi[KP];
#pragma unroll
  for (int t = 0; t < KP; ++t) { fd[t] = FLT_MAX; fi[t] = 0x7fffffff; }
  for (int c = 0; c < cnt; ++c) {
    const int j = buf[bufbase + c];
    const float2 pj = pxy[j];
    const float dot = __fadd_rn(__fmul_rn(x, pj.x), __fmul_rn(y, pj.y));
    const float d2  = __fsub_rn(__fadd_rn(s, sqs[j]), __fmul_rn(2.0f, dot));
    const float dc  = sqrtf(fmaxf(d2, 0.0f));
    if (dc < fd[KP - 1]) {
      bool shp = true;
#pragma unroll
      for (int t = KP - 1; t >= 1; --t) {
        const bool sh = dc < fd[t - 1];
        const float nd = sh ? fd[t - 1] : (shp ? dc : fd[t]);
        const int   ni = sh ? fi[t - 1] : (shp ? j  : fi[t]);
        fd[t] = nd; fi[t] = ni;
        shp = sh;
      }
      if (shp) { fd[0] = dc; fi[0] = j; }
    }
  }

  // ---------- canonical merge across lane pair (R3-verified)
  float Ad[KP], Bd[KP]; int Ai[KP], Bi[KP];
#pragma unroll
  for (int t = 0; t < KP; ++t) {
    const float o_d = __shfl_xor(fd[t], 1);
    const int   o_i = __shfl_xor(fi[t], 1);
    Ad[t] = part ? o_d : fd[t];
    Ai[t] = part ? o_i : fi[t];
    Bd[t] = part ? fd[t] : o_d;
    Bi[t] = part ? fi[t] : o_i;
  }
  float md[KP]; int mi[KP];
#pragma unroll
  for (int i = 0; i < KP; ++i) {
    const float da = Ad[i], db = Bd[KP - 1 - i];
    const int   ia = Ai[i], ib = Bi[KP - 1 - i];
    const bool aless = (da < db) || (da == db && ia < ib);
    md[i] = aless ? da : db;
    mi[i] = aless ? ia : ib;
  }
  int minpos = 0;
#pragma unroll
  for (int i = 1; i < KP; ++i) {
    const bool less = (md[i] < md[minpos]) ||
                      (md[i] == md[minpos] && mi[i] < mi[minpos]);
    minpos = less ? i : minpos;
  }
  const int base = (b * NPB + nl) * KNN;
#pragma unroll
  for (int i = 0; i < KP; ++i) {
    if ((i & 1) == part && i != minpos) {
      const int slot = i - (i > minpos ? 1 : 0);
      const int g = b * NPB + mi[i];
      nbr[base + slot] = g;
      atomicAdd(&indeg[g], 1);
    }
  }
}

// ---------------------------------------------------------------- scan
__global__ __launch_bounds__(256) void scan_phaseA(
    const int* __restrict__ indeg, int* __restrict__ bsum) {
  __shared__ int sh[256];
  const int base = blockIdx.x * SCAN_CHUNK;
  const int t = threadIdx.x;
  int sum = 0;
  for (int j = t; j < SCAN_CHUNK; j += 256) sum += indeg[base + j];
  sh[t] = sum; __syncthreads();
  for (int o = 128; o > 0; o >>= 1) {
    if (t < o) sh[t] += sh[t + o];
    __syncthreads();
  }
  if (t == 0) bsum[blockIdx.x] = sh[0];
}

// 64 threads, 128 elements: exclusive scan via wave shuffles
__global__ void scan_phaseB(int* bsum, int nb) {
  const int t = threadIdx.x;
  const int a = bsum[t * 2], b = bsum[t * 2 + 1];
  const int pair = a + b;
  int sc = pair;
  for (int o = 1; o < 64; o <<= 1) {
    const int u = __shfl_up(sc, o);
    if (t >= o) sc += u;
  }
  const int excl = sc - pair;
  bsum[t * 2] = excl;
  bsum[t * 2 + 1] = excl + a;
}

__global__ __launch_bounds__(256) void scan_phaseC(
    const int* __restrict__ indeg, const int* __restrict__ bsum,
    int* __restrict__ offs) {
  __shared__ int sh[256];
  const int base = blockIdx.x * SCAN_CHUNK;
  const int t = threadIdx.x;
  const int e0 = base + t * 4;
  const int v0 = indeg[e0], v1 = indeg[e0 + 1], v2 = indeg[e0 + 2], v3 = indeg[e0 + 3];
  const int tot = v0 + v1 + v2 + v3;
  sh[t] = tot; __syncthreads();
  for (int o = 1; o < 256; o <<= 1) {
    const int a = sh[t];
    const int bm = (t >= o) ? sh[t - o] : 0;
    __syncthreads();
    sh[t] = a + bm;
    __syncthreads();
  }
  const int pre = sh[t] - tot + bsum[blockIdx.x];
  offs[e0] = pre;
  offs[e0 + 1] = pre + v0;
  offs[e0 + 2] = pre + v0 + v1;
  offs[e0 + 3] = pre + v0 + v1 + v2;
}

// ------------------------------------------------------- CSR fill + dinv
__global__ __launch_bounds__(256) void fill_kernel(
    const int* __restrict__ nbr, const int* __restrict__ offs,
    int* __restrict__ fill, int* __restrict__ rev,
    const int* __restrict__ indeg, float* __restrict__ dinv) {
  const int i = blockIdx.x * blockDim.x + threadIdx.x;
  if (i >= NN) return;
  dinv[i] = 1.0f / sqrtf((float)(indeg[i] + 1));
#pragma unroll
  for (int k = 0; k < KNN; ++k) {
    const int v = nbr[i * KNN + k];
    const int p = offs[v] + atomicAdd(&fill[v], 1);
    rev[p] = i;
  }
}

// ---------------------------------------------------------------- GEMM
template <int KDIM>
__global__ __launch_bounds__(256) void gemm_kernel(
    const float* __restrict__ X, const float* __restrict__ W,
    float* __restrict__ H) {
  __shared__ float ws[32][DH];
  __shared__ float xs[32][32];
  const int tid = threadIdx.x;
  const int tx = tid & 31;
  const int ty = tid >> 5;
  const int rowBase = blockIdx.x * 32;
  float acc[4][4] = {};

  for (int kb = 0; kb < KDIM; kb += 32) {
    for (int l = tid; l < 32 * DH / 4; l += 256) {
      const int kk = l >> 5;
      const int cc = (l & 31) * 4;
      const float4 w4 = *(const float4*)&W[(size_t)(kb + kk) * DH + cc];
      *(float4*)&ws[kk][cc] = w4;
    }
    for (int l = tid; l < 32 * 32 / 4; l += 256) {
      const int rr = l >> 3;
      const int kk = (l & 7) * 4;
      const float4 x4 = *(const float4*)&X[((size_t)rowBase + rr) * KDIM + kb + kk];
      *(float4*)&xs[rr][kk] = x4;
    }
    __syncthreads();
#pragma unroll 8
    for (int k = 0; k < 32; ++k) {
      const float4 w4 = *(const float4*)&ws[k][tx * 4];
      const float a0 = xs[ty * 4 + 0][k];
      const float a1 = xs[ty * 4 + 1][k];
      const float a2 = xs[ty * 4 + 2][k];
      const float a3 = xs[ty * 4 + 3][k];
      acc[0][0] += a0 * w4.x; acc[0][1] += a0 * w4.y; acc[0][2] += a0 * w4.z; acc[0][3] += a0 * w4.w;
      acc[1][0] += a1 * w4.x; acc[1][1] += a1 * w4.y; acc[1][2] += a1 * w4.z; acc[1][3] += a1 * w4.w;
      acc[2][0] += a2 * w4.x; acc[2][1] += a2 * w4.y; acc[2][2] += a2 * w4.z; acc[2][3] += a2 * w4.w;
      acc[3][0] += a3 * w4.x; acc[3][1] += a3 * w4.y; acc[3][2] += a3 * w4.z; acc[3][3] += a3 * w4.w;
    }
    __syncthreads();
  }
#pragma unroll
  for (int r = 0; r < 4; ++r) {
    const float4 o = make_float4(acc[r][0], acc[r][1], acc[r][2], acc[r][3]);
    *(float4*)&H[((size_t)rowBase + ty * 4 + r) * DH + tx * 4] = o;
  }
}

// ------------------------------------------------------------- aggregate
// One wave per node; lane = (edge-parity, float4 chunk): 32 lanes x 16B
// cover a 128-dim row; two neighbor rows in flight per iteration.
__global__ __launch_bounds__(256) void agg_kernel(
    const float* __restrict__ H, const int* __restrict__ offs,
    const int* __restrict__ indeg, const int* __restrict__ rev,
    const float* __restrict__ dinv, const float* __restrict__ bias,
    float* __restrict__ Xout) {
  const int gtid = blockIdx.x * blockDim.x + threadIdx.x;
  const int v = gtid >> 6;
  if (v >= NN) return;
  const int lane = threadIdx.x & 63;
  const int half = lane >> 5;          // edge parity this lane serves
  const int q = lane & 31;             // float4 chunk within the row
  const float dv = dinv[v];

  float4 acc = make_float4(0.f, 0.f, 0.f, 0.f);
  if (half == 0) {                     // self term once
    const float4 hs = *((const float4*)(H + (size_t)v * DH) + q);
    const float w = dv * dv;
    acc.x = hs.x * w; acc.y = hs.y * w; acc.z = hs.z * w; acc.w = hs.w * w;
  }
  const int beg = offs[v];
  const int len = indeg[v];
  for (int e = half; e < len; e += 2) {
    const int i = rev[beg + e];
    const float sc = dinv[i] * dv;
    const float4 h4 = *((const float4*)(H + (size_t)i * DH) + q);
    acc.x += h4.x * sc; acc.y += h4.y * sc;
    acc.z += h4.z * sc; acc.w += h4.w * sc;
  }
  // combine the two halves
  acc.x += __shfl_xor(acc.x, 32);
  acc.y += __shfl_xor(acc.y, 32);
  acc.z += __shfl_xor(acc.z, 32);
  acc.w += __shfl_xor(acc.w, 32);
  if (half == 0) {
    const float4 b4 = *((const float4*)bias + q);
    float4 o;
    o.x = tanhf(acc.x + b4.x);
    o.y = tanhf(acc.y + b4.y);
    o.z = tanhf(acc.z + b4.z);
    o.w = tanhf(acc.w + b4.w);
    *((float4*)(Xout + (size_t)v * DH) + q) = o;
  }
}

// ------------------------------------------------------------ output head
__global__ __launch_bounds__(256) void out_kernel(
    const float* __restrict__ X, const float* __restrict__ Wout,
    const float* __restrict__ bout, float* __restrict__ out) {
  __shared__ float ws[DH * DOUT];
  __shared__ float bs[DOUT];
  const int tid = threadIdx.x;
  for (int l = tid; l < DH * DOUT; l += 256) ws[l] = Wout[l];
  if (tid < DOUT) bs[tid] = bout[tid];
  __syncthreads();
  const int node = blockIdx.x * 256 + tid;
  float acc[DOUT];
#pragma unroll
  for (int o = 0; o < DOUT; ++o) acc[o] = bs[o];
  const float4* xr = (const float4*)(X + (size_t)node * DH);
#pragma unroll 4
  for (int k4 = 0; k4 < DH / 4; ++k4) {
    const float4 x4 = xr[k4];
#pragma unroll
    for (int o = 0; o < DOUT; ++o) {
      acc[o] += x4.x * ws[(k4 * 4 + 0) * DOUT + o]
              + x4.y * ws[(k4 * 4 + 1) * DOUT + o]
              + x4.z * ws[(k4 * 4 + 2) * DOUT + o]
              + x4.w * ws[(k4 * 4 + 3) * DOUT + o];
    }
  }
  float4* op = (float4*)(out + (size_t)node * DOUT);
  op[0] = make_float4(acc[0], acc[1], acc[2], acc[3]);
  op[1] = make_float4(acc[4], acc[5], acc[6], acc[7]);
}

// ---------------------------------------------------------------- launch
extern "C" void kernel_launch(void* const* d_in, const int* in_sizes, int n_in,
                              void* d_out, int out_size, void* d_ws, size_t ws_size,
                              hipStream_t stream) {
  const float* obs  = (const float*)d_in[0];
  const float* W1   = (const float*)d_in[1];
  const float* b1   = (const float*)d_in[2];
  const float* W2   = (const float*)d_in[3];
  const float* b2   = (const float*)d_in[4];
  const float* Wout = (const float*)d_in[5];
  const float* bout = (const float*)d_in[6];
  float* out = (float*)d_out;

  char* p = (char*)d_ws;
  auto carve = [&](size_t bytes) {
    void* r = (void*)p;
    p += (bytes + 255) / 256 * 256;
    return r;
  };
  float* h    = (float*)carve((size_t)NN * DH * 4);
  float* x1   = (float*)carve((size_t)NN * DH * 4);
  int*   nbr  = (int*)carve((size_t)NN * KNN * 4);
  int*   indeg= (int*)carve((size_t)NN * 4);
  int*   offs = (int*)carve((size_t)NN * 4);
  int*   fil  = (int*)carve((size_t)NN * 4);
  int*   rev  = (int*)carve((size_t)NN * KNN * 4);
  float* dinv = (float*)carve((size_t)NN * 4);
  int*   bsum = (int*)carve(256 * 4);

  hipMemsetAsync(indeg, 0, (size_t)NN * 4, stream);
  hipMemsetAsync(fil,   0, (size_t)NN * 4, stream);

  // graph build
  knn_kernel<<<BATCHES * 4, 256, 0, stream>>>(obs, nbr, indeg);
  scan_phaseA<<<NN / SCAN_CHUNK, 256, 0, stream>>>(indeg, bsum);
  scan_phaseB<<<1, 64, 0, stream>>>(bsum, NN / SCAN_CHUNK);
  scan_phaseC<<<NN / SCAN_CHUNK, 256, 0, stream>>>(indeg, bsum, offs);
  fill_kernel<<<NN / 256, 256, 0, stream>>>(nbr, offs, fil, rev, indeg, dinv);

  // layer 1: h = obs @ W1 ; x1 = tanh(agg + b1)
  gemm_kernel<DIN><<<NN / 32, 256, 0, stream>>>(obs, W1, h);
  agg_kernel<<<NN * 64 / 256, 256, 0, stream>>>(h, offs, indeg, rev, dinv, b1, x1);

  // layer 2: h = x1 @ W2 ; x1 = tanh(agg + b2)
  gemm_kernel<DH><<<NN / 32, 256, 0, stream>>>(x1, W2, h);
  agg_kernel<<<NN * 64 / 256, 256, 0, stream>>>(h, offs, indeg, rev, dinv, b2, x1);

  // output head
  out_kernel<<<NN / 256, 256, 0, stream>>>(x1, Wout, bout, out);
}

// Round 5
// 529.317 us; speedup vs baseline: 1.7630x; 1.1625x over previous
//
#include <hip/hip_runtime.h>
#include <hip/hip_bf16.h>
#include <float.h>

#define BATCHES 256
#define NPB     512            // nodes per batch
#define NN      (BATCHES*NPB)  // 131072 total nodes
#define KNN     16
#define KP      17
#define DIN     32
#define DH      128
#define DOUT    8
#define BUFS    24             // phase-2 collection slots per thread
#define REVC    64             // reverse-adjacency capacity per node

// ---------------------------------------------------------------- KNN
// 2 threads/node over disjoint 256-candidate halves.
// P1: top-17 d2 values via PAIR bubble: insert 2 candidates per pass with
//     (min, v_med3, max) = 3 ops/slot. d2 arithmetic reference-exact.
// thr: 17th-smallest d2 of the pair union (bitonic half-clean max).
// P2: collect j with max(d2,0) <= max(thr2,0)  (== dc <= thr, no sqrt).
// Final: exact lex (dist,idx) top-17 + R3-verified canonical merge.
// Emits edges directly into fixed-capacity reverse lists (no CSR pass).
__global__ __launch_bounds__(256) void knn_kernel(
    const float* __restrict__ obs, int* __restrict__ fill, int* __restrict__ rev) {
  __shared__ float4 cand[NPB];                 // {x, y, sq, -}  8 KiB
  __shared__ unsigned short buf[256 * BUFS];   // 12 KiB
  const int b = blockIdx.x >> 2;
  const int quarter = blockIdx.x & 3;
  const int tid = threadIdx.x;
  const int part = tid & 1;
  const int nl = (tid >> 1) + quarter * 128;

  for (int l = tid; l < NPB; l += 256) {
    const float* orow = obs + ((size_t)b * NPB + l) * DIN;
    const float xx = orow[0], yy = orow[1];
    const float sq = __fadd_rn(__fmul_rn(xx, xx), __fmul_rn(yy, yy));
    cand[l] = make_float4(xx, yy, sq, 0.0f);
  }
  __syncthreads();

  const float4 me = cand[nl];
  const float x = me.x, y = me.y, s = me.z;
  const int jbase = part * 256;

  // ---------- phase 1: top-17 d2 values, 2 candidates per bubble pass
  float dl[KP];
#pragma unroll
  for (int t = 0; t < KP; ++t) dl[t] = FLT_MAX;

  for (int jj = 0; jj < 256; jj += 2) {
    const float4 ca = cand[jbase + jj];
    const float4 cb = cand[jbase + jj + 1];
    const float dota = __fadd_rn(__fmul_rn(x, ca.x), __fmul_rn(y, ca.y));
    const float d2a  = __fsub_rn(__fadd_rn(s, ca.z), __fmul_rn(2.0f, dota));
    const float dotb = __fadd_rn(__fmul_rn(x, cb.x), __fmul_rn(y, cb.y));
    const float d2b  = __fsub_rn(__fadd_rn(s, cb.z), __fmul_rn(2.0f, dotb));
    float c0 = fminf(d2a, d2b);
    float c1 = fmaxf(d2a, d2b);
#pragma unroll
    for (int t = 0; t < KP; ++t) {
      const float mn = fminf(dl[t], c0);
      float md;
      asm("v_med3_f32 %0, %1, %2, %3" : "=v"(md) : "v"(dl[t]), "v"(c0), "v"(c1));
      c1 = fmaxf(dl[t], c1);
      dl[t] = mn;
      c0 = md;
    }
  }

  // ---------- threshold: 17th-smallest d2 of lane-pair union
  float thr2 = -FLT_MAX;
#pragma unroll
  for (int i = 0; i < KP; ++i) {
    const float ob = __shfl_xor(dl[KP - 1 - i], 1);
    thr2 = fmaxf(thr2, fminf(dl[i], ob));
  }
  const float thr2c = fmaxf(thr2, 0.0f);

  // ---------- phase 2: collect candidates (no sqrt; order-equivalent)
  int cnt = 0;
  const int bufbase = tid * BUFS;
  for (int jj = 0; jj < 256; ++jj) {
    const int j = jbase + jj;
    const float4 c = cand[j];
    const float dot = __fadd_rn(__fmul_rn(x, c.x), __fmul_rn(y, c.y));
    const float d2  = __fsub_rn(__fadd_rn(s, c.z), __fmul_rn(2.0f, dot));
    if (fmaxf(d2, 0.0f) <= thr2c && cnt < BUFS) {
      buf[bufbase + cnt] = (unsigned short)j;
      ++cnt;
    }
  }

  // ---------- final: exact lex (dist,idx) top-17 of collected items
  float fd[KP]; int fi[KP];
#pragma unroll
  for (int t = 0; t < KP; ++t) { fd[t] = FLT_MAX; fi[t] = 0x7fffffff; }
  for (int c = 0; c < cnt; ++c) {
    const int j = buf[bufbase + c];
    const float4 pj = cand[j];
    const float dot = __fadd_rn(__fmul_rn(x, pj.x), __fmul_rn(y, pj.y));
    const float d2  = __fsub_rn(__fadd_rn(s, pj.z), __fmul_rn(2.0f, dot));
    const float dc  = sqrtf(fmaxf(d2, 0.0f));
    if (dc < fd[KP - 1]) {
      bool shp = true;
#pragma unroll
      for (int t = KP - 1; t >= 1; --t) {
        const bool sh = dc < fd[t - 1];
        const float nd = sh ? fd[t - 1] : (shp ? dc : fd[t]);
        const int   ni = sh ? fi[t - 1] : (shp ? j  : fi[t]);
        fd[t] = nd; fi[t] = ni;
        shp = sh;
      }
      if (shp) { fd[0] = dc; fi[0] = j; }
    }
  }

  // ---------- canonical merge across lane pair (R3-verified)
  float Ad[KP], Bd[KP]; int Ai[KP], Bi[KP];
#pragma unroll
  for (int t = 0; t < KP; ++t) {
    const float o_d = __shfl_xor(fd[t], 1);
    const int   o_i = __shfl_xor(fi[t], 1);
    Ad[t] = part ? o_d : fd[t];
    Ai[t] = part ? o_i : fi[t];
    Bd[t] = part ? fd[t] : o_d;
    Bi[t] = part ? fi[t] : o_i;
  }
  float md[KP]; int mi[KP];
#pragma unroll
  for (int i = 0; i < KP; ++i) {
    const float da = Ad[i], db = Bd[KP - 1 - i];
    const int   ia = Ai[i], ib = Bi[KP - 1 - i];
    const bool aless = (da < db) || (da == db && ia < ib);
    md[i] = aless ? da : db;
    mi[i] = aless ? ia : ib;
  }
  int minpos = 0;
#pragma unroll
  for (int i = 1; i < KP; ++i) {
    const bool less = (md[i] < md[minpos]) ||
                      (md[i] == md[minpos] && mi[i] < mi[minpos]);
    minpos = less ? i : minpos;
  }
  // emit edges: src = this node, dst = neighbor; scatter into rev[dst]
  const int src = b * NPB + nl;
#pragma unroll
  for (int i = 0; i < KP; ++i) {
    if ((i & 1) == part && i != minpos) {
      const int g = b * NPB + mi[i];
      const int slot = atomicAdd(&fill[g], 1);
      if (slot < REVC) rev[(size_t)g * REVC + slot] = src;
    }
  }
}

// ---------------------------------------------------------------- GEMM
// Block computes 32 rows x 128 cols. Thread = 4 rows x 4 cols.
// DINV epilogue (layer 1 only): dinv[row] = rsqrt(indeg+1).
template <int KDIM, bool DINV>
__global__ __launch_bounds__(256) void gemm_kernel(
    const float* __restrict__ X, const float* __restrict__ W,
    float* __restrict__ H, const int* __restrict__ fill,
    float* __restrict__ dinv) {
  __shared__ float ws[32][DH];
  __shared__ float xs[32][32];
  const int tid = threadIdx.x;
  const int tx = tid & 31;
  const int ty = tid >> 5;
  const int rowBase = blockIdx.x * 32;
  float acc[4][4] = {};

  for (int kb = 0; kb < KDIM; kb += 32) {
    for (int l = tid; l < 32 * DH / 4; l += 256) {
      const int kk = l >> 5;
      const int cc = (l & 31) * 4;
      const float4 w4 = *(const float4*)&W[(size_t)(kb + kk) * DH + cc];
      *(float4*)&ws[kk][cc] = w4;
    }
    for (int l = tid; l < 32 * 32 / 4; l += 256) {
      const int rr = l >> 3;
      const int kk = (l & 7) * 4;
      const float4 x4 = *(const float4*)&X[((size_t)rowBase + rr) * KDIM + kb + kk];
      *(float4*)&xs[rr][kk] = x4;
    }
    __syncthreads();
#pragma unroll 8
    for (int k = 0; k < 32; ++k) {
      const float4 w4 = *(const float4*)&ws[k][tx * 4];
      const float a0 = xs[ty * 4 + 0][k];
      const float a1 = xs[ty * 4 + 1][k];
      const float a2 = xs[ty * 4 + 2][k];
      const float a3 = xs[ty * 4 + 3][k];
      acc[0][0] += a0 * w4.x; acc[0][1] += a0 * w4.y; acc[0][2] += a0 * w4.z; acc[0][3] += a0 * w4.w;
      acc[1][0] += a1 * w4.x; acc[1][1] += a1 * w4.y; acc[1][2] += a1 * w4.z; acc[1][3] += a1 * w4.w;
      acc[2][0] += a2 * w4.x; acc[2][1] += a2 * w4.y; acc[2][2] += a2 * w4.z; acc[2][3] += a2 * w4.w;
      acc[3][0] += a3 * w4.x; acc[3][1] += a3 * w4.y; acc[3][2] += a3 * w4.z; acc[3][3] += a3 * w4.w;
    }
    __syncthreads();
  }
#pragma unroll
  for (int r = 0; r < 4; ++r) {
    const float4 o = make_float4(acc[r][0], acc[r][1], acc[r][2], acc[r][3]);
    *(float4*)&H[((size_t)rowBase + ty * 4 + r) * DH + tx * 4] = o;
  }
  if (DINV && tid < 32) {
    const int node = rowBase + tid;
    dinv[node] = rsqrtf((float)fill[node] + 1.0f);
  }
}

// ------------------------------------------------------------- aggregate
// One wave per node; lane = (edge-parity half, float4 chunk q).
// HEAD=false: write tanh(agg+bias) to Xout.
// HEAD=true:  fuse output head: out[v] = tanh(agg+bias) @ Wout + bout.
template <bool HEAD>
__global__ __launch_bounds__(256) void agg_kernel(
    const float* __restrict__ H, const int* __restrict__ fill,
    const int* __restrict__ rev, const float* __restrict__ dinv,
    const float* __restrict__ bias, const float* __restrict__ Wout,
    const float* __restrict__ bout, float* __restrict__ Xout) {
  const int gtid = blockIdx.x * blockDim.x + threadIdx.x;
  const int v = gtid >> 6;
  if (v >= NN) return;
  const int lane = threadIdx.x & 63;
  const int half = lane >> 5;
  const int q = lane & 31;
  const float dv = dinv[v];

  float4 acc = make_float4(0.f, 0.f, 0.f, 0.f);
  if (half == 0) {                     // self term once
    const float4 hs = *((const float4*)(H + (size_t)v * DH) + q);
    const float w = dv * dv;
    acc.x = hs.x * w; acc.y = hs.y * w; acc.z = hs.z * w; acc.w = hs.w * w;
  }
  const int len0 = fill[v];
  const int len = len0 < REVC ? len0 : REVC;
  const size_t beg = (size_t)v * REVC;
  for (int e = half; e < len; e += 2) {
    const int i = rev[beg + e];
    const float sc = dinv[i] * dv;
    const float4 h4 = *((const float4*)(H + (size_t)i * DH) + q);
    acc.x += h4.x * sc; acc.y += h4.y * sc;
    acc.z += h4.z * sc; acc.w += h4.w * sc;
  }
  // combine halves (both halves end up with the full sum)
  acc.x += __shfl_xor(acc.x, 32);
  acc.y += __shfl_xor(acc.y, 32);
  acc.z += __shfl_xor(acc.z, 32);
  acc.w += __shfl_xor(acc.w, 32);

  const float4 b4 = *((const float4*)bias + q);
  float4 t;
  t.x = tanhf(acc.x + b4.x);
  t.y = tanhf(acc.y + b4.y);
  t.z = tanhf(acc.z + b4.z);
  t.w = tanhf(acc.w + b4.w);

  if (!HEAD) {
    if (half == 0) *((float4*)(Xout + (size_t)v * DH) + q) = t;
  } else {
    // half h computes outs 4h..4h+3: po[oo] = sum_j t[j]*Wout[4q+j][4h+oo]
    const float4 w0 = *(const float4*)&Wout[(4 * q + 0) * DOUT + 4 * half];
    const float4 w1 = *(const float4*)&Wout[(4 * q + 1) * DOUT + 4 * half];
    const float4 w2 = *(const float4*)&Wout[(4 * q + 2) * DOUT + 4 * half];
    const float4 w3 = *(const float4*)&Wout[(4 * q + 3) * DOUT + 4 * half];
    float4 po;
    po.x = t.x * w0.x + t.y * w1.x + t.z * w2.x + t.w * w3.x;
    po.y = t.x * w0.y + t.y * w1.y + t.z * w2.y + t.w * w3.y;
    po.z = t.x * w0.z + t.y * w1.z + t.z * w2.z + t.w * w3.z;
    po.w = t.x * w0.w + t.y * w1.w + t.z * w2.w + t.w * w3.w;
#pragma unroll
    for (int off = 16; off >= 1; off >>= 1) {
      po.x += __shfl_xor(po.x, off);
      po.y += __shfl_xor(po.y, off);
      po.z += __shfl_xor(po.z, off);
      po.w += __shfl_xor(po.w, off);
    }
    if (q == 0) {
      const float4 bo = *(const float4*)&bout[4 * half];
      po.x += bo.x; po.y += bo.y; po.z += bo.z; po.w += bo.w;
      *(float4*)(Xout + (size_t)v * DOUT + 4 * half) = po;
    }
  }
}

// ---------------------------------------------------------------- launch
extern "C" void kernel_launch(void* const* d_in, const int* in_sizes, int n_in,
                              void* d_out, int out_size, void* d_ws, size_t ws_size,
                              hipStream_t stream) {
  const float* obs  = (const float*)d_in[0];
  const float* W1   = (const float*)d_in[1];
  const float* b1   = (const float*)d_in[2];
  const float* W2   = (const float*)d_in[3];
  const float* b2   = (const float*)d_in[4];
  const float* Wout = (const float*)d_in[5];
  const float* bout = (const float*)d_in[6];
  float* out = (float*)d_out;

  char* p = (char*)d_ws;
  auto carve = [&](size_t bytes) {
    void* r = (void*)p;
    p += (bytes + 255) / 256 * 256;
    return r;
  };
  float* h    = (float*)carve((size_t)NN * DH * 4);       // 67 MB
  float* x1   = (float*)carve((size_t)NN * DH * 4);       // 67 MB
  int*   rev  = (int*)carve((size_t)NN * REVC * 4);       // 33.5 MB
  int*   fill = (int*)carve((size_t)NN * 4);
  float* dinv = (float*)carve((size_t)NN * 4);

  hipMemsetAsync(fill, 0, (size_t)NN * 4, stream);

  // graph build: knn + direct reverse-adjacency scatter
  knn_kernel<<<BATCHES * 4, 256, 0, stream>>>(obs, fill, rev);

  // layer 1: h = obs @ W1 (+ dinv epilogue) ; x1 = tanh(agg + b1)
  gemm_kernel<DIN, true><<<NN / 32, 256, 0, stream>>>(obs, W1, h, fill, dinv);
  agg_kernel<false><<<NN * 64 / 256, 256, 0, stream>>>(
      h, fill, rev, dinv, b1, nullptr, nullptr, x1);

  // layer 2: h = x1 @ W2 ; out = tanh(agg + b2) @ Wout + bout  (fused head)
  gemm_kernel<DH, false><<<NN / 32, 256, 0, stream>>>(x1, W2, h, nullptr, nullptr);
  agg_kernel<true><<<NN * 64 / 256, 256, 0, stream>>>(
      h, fill, rev, dinv, b2, Wout, bout, out);
}